// Round 6
// baseline (50.048 us; speedup 1.0000x reference)
//
#include <hip/hip_runtime.h>
#include <hip/hip_bf16.h>
#include <math.h>

// DDRFMixer: out[b,t,d] = sum_n softmax_n(x[b,t,:]·W[n,:]) * x[b,t-off_n,d]
// x: [B,T,D] fp32, W: [7,D] fp32, out: [B,T,D] fp32
// B=4, T=4096, D=1024, offsets = {1,2,4,8,16,32,64}
//
// R5 = R4 with the nontemporal-store compile fix (native ext_vector_type,
// not HIP_vector_type, for __builtin_nontemporal_store).
//
// Structure:
//  - W staged in LDS once per block (28 KB). R3 read W from global every row:
//    28 KB/row through a 32 KB L1 -> W and streaming x evicted each other
//    (L1-BW bound). LDS pipe runs parallel to VMEM pipe.
//  - One wave per row, 4 consecutive rows per wave, 16 rows per block.
//  - XCD-aware bijective block swizzle: each XCD owns a contiguous 2048-row
//    chunk so the 64-row tap window is local-L2.
//  - Nontemporal output stores (out is never re-read; don't evict taps).

#define N_TAPS 7
#define DIM 1024
#define T_LEN 4096
#define ROWS_PER_BLOCK 16
#define ROWS_PER_WAVE 4

typedef float floatx4 __attribute__((ext_vector_type(4)));

__global__ __launch_bounds__(256) void ddrf_mixer_kernel(
    const float* __restrict__ x,   // [B*T, D]
    const float* __restrict__ W,   // [N_TAPS, D]
    float* __restrict__ out,       // [B*T, D]
    int n_rows)
{
    constexpr int offs[N_TAPS] = {1, 2, 4, 8, 16, 32, 64};

    __shared__ float wlds[N_TAPS * DIM];   // 28 KB

    // ---- stage W into LDS (once per block) ----
    {
        const int tid = threadIdx.x;                 // 0..255
#pragma unroll
        for (int r = 0; r < N_TAPS; ++r) {
            const int idx = r * DIM + tid * 4;       // 256 thr * 4 = 1024/row
            *reinterpret_cast<float4*>(&wlds[idx]) =
                *reinterpret_cast<const float4*>(&W[idx]);
        }
    }
    __syncthreads();

    // ---- bijective XCD swizzle (gridDim.x % 8 == 0) ----
    const int per = gridDim.x >> 3;
    const int wg  = (blockIdx.x & 7) * per + (blockIdx.x >> 3);

    const int wave = threadIdx.x >> 6;
    const int lane = threadIdx.x & 63;
    const int dofs = lane * 4;               // lane's base within each 256-chunk

    const int row0 = wg * ROWS_PER_BLOCK + wave * ROWS_PER_WAVE;

#pragma unroll
    for (int rr = 0; rr < ROWS_PER_WAVE; ++rr) {
        const int row = row0 + rr;
        if (row >= n_rows) continue;          // wave-uniform
        const int t = row & (T_LEN - 1);
        const float* xrow = x + (size_t)row * DIM;

        // ---- load this row's 16 elements (4 strided float4) ----
        float4 xv[4];
#pragma unroll
        for (int k = 0; k < 4; ++k)
            xv[k] = *reinterpret_cast<const float4*>(xrow + k * 256 + dofs);

        // ---- Phase 1: partial dots vs W (from LDS) ----
        float p[N_TAPS];
#pragma unroll
        for (int n = 0; n < N_TAPS; ++n) {
            const float* wrow = &wlds[n * DIM];
            float4 w0 = *reinterpret_cast<const float4*>(wrow + 0 * 256 + dofs);
            float4 w1 = *reinterpret_cast<const float4*>(wrow + 1 * 256 + dofs);
            float4 w2 = *reinterpret_cast<const float4*>(wrow + 2 * 256 + dofs);
            float4 w3 = *reinterpret_cast<const float4*>(wrow + 3 * 256 + dofs);
            float s0 = fmaf(xv[0].x, w0.x, fmaf(xv[0].y, w0.y, fmaf(xv[0].z, w0.z, xv[0].w * w0.w)));
            float s1 = fmaf(xv[1].x, w1.x, fmaf(xv[1].y, w1.y, fmaf(xv[1].z, w1.z, xv[1].w * w1.w)));
            float s2 = fmaf(xv[2].x, w2.x, fmaf(xv[2].y, w2.y, fmaf(xv[2].z, w2.z, xv[2].w * w2.w)));
            float s3 = fmaf(xv[3].x, w3.x, fmaf(xv[3].y, w3.y, fmaf(xv[3].z, w3.z, xv[3].w * w3.w)));
            p[n] = (s0 + s1) + (s2 + s3);
        }

        // ---- wave-level butterfly reduce (64 lanes), 7 independent chains ----
#pragma unroll
        for (int n = 0; n < N_TAPS; ++n) {
#pragma unroll
            for (int m = 32; m >= 1; m >>= 1)
                p[n] += __shfl_xor(p[n], m, 64);
        }

        // ---- softmax over 7 taps (redundant per lane, cheap) ----
        float mx = p[0];
#pragma unroll
        for (int n = 1; n < N_TAPS; ++n) mx = fmaxf(mx, p[n]);
        float wn[N_TAPS];
        float wsum = 0.f;
#pragma unroll
        for (int n = 0; n < N_TAPS; ++n) {
            wn[n] = __expf(p[n] - mx);
            wsum += wn[n];
        }
        const float inv = 1.0f / wsum;

        // ---- Phase 2: weighted sum of past taps ----
        float4 acc[4];
#pragma unroll
        for (int k = 0; k < 4; ++k) acc[k] = make_float4(0.f, 0.f, 0.f, 0.f);

#pragma unroll
        for (int n = 0; n < N_TAPS; ++n) {
            const int off = offs[n];
            if (t >= off) {                   // wave-uniform branch
                const float* trow = xrow - (size_t)off * DIM;
                const float w = wn[n] * inv;
#pragma unroll
                for (int k = 0; k < 4; ++k) {
                    const float4 tv =
                        *reinterpret_cast<const float4*>(trow + k * 256 + dofs);
                    acc[k].x = fmaf(w, tv.x, acc[k].x);
                    acc[k].y = fmaf(w, tv.y, acc[k].y);
                    acc[k].z = fmaf(w, tv.z, acc[k].z);
                    acc[k].w = fmaf(w, tv.w, acc[k].w);
                }
            }
        }

        // ---- nontemporal store (out never re-read; keep caches for taps) ----
        float* orow = out + (size_t)row * DIM;
#pragma unroll
        for (int k = 0; k < 4; ++k) {
            floatx4 v = { acc[k].x, acc[k].y, acc[k].z, acc[k].w };
            __builtin_nontemporal_store(v,
                reinterpret_cast<floatx4*>(orow + k * 256 + dofs));
        }
    }
}

extern "C" void kernel_launch(void* const* d_in, const int* in_sizes, int n_in,
                              void* d_out, int out_size, void* d_ws, size_t ws_size,
                              hipStream_t stream) {
    const float* x = (const float*)d_in[0];   // [B,T,D] fp32
    const float* W = (const float*)d_in[1];   // [N_TAPS,D] fp32
    float* out = (float*)d_out;               // [B,T,D] fp32

    const int n_rows   = in_sizes[0] / DIM;          // B*T = 16384
    const int n_blocks = n_rows / ROWS_PER_BLOCK;    // 1024 (divisible by 8)

    ddrf_mixer_kernel<<<n_blocks, 256, 0, stream>>>(x, W, out, n_rows);
}